// Round 3
// baseline (133.477 us; speedup 1.0000x reference)
//
#include <hip/hip_runtime.h>
#include <hip/hip_bf16.h>

// Problem constants (fixed by setup_inputs)
#define B 4
#define T 1024
#define D 512
#define U 32
#define WIN 64           // attention window (j in [t-32, t+31])
#define EPS 1e-7f

// ---------------------------------------------------------------------------
// Kernel A: qk[row][0:32]  = x[row,:] @ Wt + bh   (q, bias folded)
//           qk[row][32:64] = x[row,:] @ Wx        (k)
// Block: 256 thr = 4 waves, 16 rows/block (4 rows/wave), 256 blocks.
// W staged in LDS as W2[d][0:32]=Wt[d][:], W2[d][32:64]=Wx[d][:], in two
// half-D passes (64 KB LDS each). Lane = output column; per d: one
// conflict-free ds_read_b32 + 4 FMAs; x[row][d] is wave-uniform (s_load).
// W global traffic: 256 blocks x 128 KB = 32 MB (was 512 MB).
// ---------------------------------------------------------------------------
__global__ __launch_bounds__(256) void qk_kernel(
    const float* __restrict__ x, const float* __restrict__ Wt,
    const float* __restrict__ Wx, const float* __restrict__ bh,
    float* __restrict__ qk)
{
    __shared__ float W2[D / 2][64];      // 64 KB

    const int tid  = threadIdx.x;
    const int lane = tid & 63;
    const int wv   = tid >> 6;
    const int row0 = blockIdx.x * 16 + wv * 4;

    const float bias = (lane < U) ? bh[lane] : 0.0f;
    float a0 = bias, a1 = bias, a2 = bias, a3 = bias;

    const float* x0 = x + (size_t)(row0 + 0) * D;
    const float* x1 = x + (size_t)(row0 + 1) * D;
    const float* x2 = x + (size_t)(row0 + 2) * D;
    const float* x3 = x + (size_t)(row0 + 3) * D;

    for (int h = 0; h < 2; ++h) {
        // ---- stage this half of Wt|Wx into LDS ----
        const float4* WtV = (const float4*)(Wt + (size_t)h * (D / 2) * U);
        const float4* WxV = (const float4*)(Wx + (size_t)h * (D / 2) * U);
        #pragma unroll
        for (int i = 0; i < (D / 2) * U / 4 / 256; ++i) {   // 8 iters
            const int idx = tid + i * 256;
            const int d   = (idx << 2) >> 5;    // local d
            const int u   = (idx << 2) & 31;
            float4 v = WtV[idx];
            W2[d][u + 0] = v.x; W2[d][u + 1] = v.y;
            W2[d][u + 2] = v.z; W2[d][u + 3] = v.w;
            float4 w = WxV[idx];
            W2[d][32 + u + 0] = w.x; W2[d][32 + u + 1] = w.y;
            W2[d][32 + u + 2] = w.z; W2[d][32 + u + 3] = w.w;
        }
        __syncthreads();

        const float* xp0 = x0 + h * (D / 2);
        const float* xp1 = x1 + h * (D / 2);
        const float* xp2 = x2 + h * (D / 2);
        const float* xp3 = x3 + h * (D / 2);

        #pragma unroll 8
        for (int dd = 0; dd < D / 2; ++dd) {
            const float w = W2[dd][lane];
            a0 = fmaf(xp0[dd], w, a0);
            a1 = fmaf(xp1[dd], w, a1);
            a2 = fmaf(xp2[dd], w, a2);
            a3 = fmaf(xp3[dd], w, a3);
        }
        __syncthreads();   // before next half overwrites W2
    }

    qk[(size_t)(row0 + 0) * WIN + lane] = a0;
    qk[(size_t)(row0 + 1) * WIN + lane] = a1;
    qk[(size_t)(row0 + 2) * WIN + lane] = a2;
    qk[(size_t)(row0 + 3) * WIN + lane] = a3;
}

// ---------------------------------------------------------------------------
// Kernel B: wave = (b,t, d-half). 2048 blocks x 4 waves = 8192 waves (100%
// of wave slots; was 50%). Phase 1 (scores) duplicated across the 2 waves
// of each t — tanh is cheap. Phase 2: each wave accumulates one float4/lane
// over its 256-wide d-half.
// ---------------------------------------------------------------------------
__global__ __launch_bounds__(256) void attn_kernel(
    const float* __restrict__ x, const float* __restrict__ qk,
    const float* __restrict__ Wa, const float* __restrict__ ba,
    float* __restrict__ out)
{
    const int tid  = threadIdx.x;
    const int lane = tid & 63;
    const int wv   = tid >> 6;            // 0..3
    const int gt   = blockIdx.x * 2 + (wv >> 1);   // 0 .. B*T-1
    const int dh   = wv & 1;              // d-half
    const int b    = gt >> 10;
    const int t    = gt & (T - 1);

    const float* qrow = qk + (size_t)gt * WIN;

    // ---- Phase 1: scores ----
    const int jj = t - 32 + lane;
    const bool valid = (jj >= 0) && (jj < T);
    float e = 0.0f;
    if (valid) {
        const float* krow = qk + ((size_t)(b * T + jj)) * WIN + U;
        float4 kv[8];
        #pragma unroll
        for (int i = 0; i < 8; ++i) kv[i] = ((const float4*)krow)[i];
        float acc = ba[0];
        #pragma unroll
        for (int u = 0; u < U; ++u) {
            const float z  = qrow[u] + ((const float*)kv)[u];
            const float ez = __expf(2.0f * z);
            const float hh = 1.0f - 2.0f / (ez + 1.0f);   // tanh(z)
            acc = fmaf(Wa[u], hh, acc);
        }
        e = __expf(acc);
    }

    float s = e;
    #pragma unroll
    for (int off = 32; off > 0; off >>= 1)
        s += __shfl_xor(s, off);
    const float a = e / (s + EPS);

    // ---- Phase 2: weighted sum of x rows over this d-half ----
    const int j0 = (t < 32) ? (32 - t) : 0;
    const int j1 = (T + 32 - t < WIN) ? (T + 32 - t) : WIN;

    float4 v = make_float4(0.f, 0.f, 0.f, 0.f);
    const float* xb = x + (size_t)b * T * D + dh * (D / 2);

    for (int j = j0; j < j1; ++j) {
        const float aj = __shfl(a, j);
        const float4 xv = ((const float4*)(xb + (size_t)(t - 32 + j) * D))[lane];
        v.x = fmaf(aj, xv.x, v.x);
        v.y = fmaf(aj, xv.y, v.y);
        v.z = fmaf(aj, xv.z, v.z);
        v.w = fmaf(aj, xv.w, v.w);
    }

    ((float4*)(out + (size_t)gt * D + dh * (D / 2)))[lane] = v;
}

extern "C" void kernel_launch(void* const* d_in, const int* in_sizes, int n_in,
                              void* d_out, int out_size, void* d_ws, size_t ws_size,
                              hipStream_t stream)
{
    const float* x  = (const float*)d_in[0];
    const float* Wt = (const float*)d_in[1];
    const float* Wx = (const float*)d_in[2];
    const float* bh = (const float*)d_in[3];
    const float* Wa = (const float*)d_in[4];
    const float* ba = (const float*)d_in[5];
    float* out = (float*)d_out;
    float* qk  = (float*)d_ws;   // B*T*64 floats = 1 MB

    const int rows = B * T;                 // 4096
    dim3 blk(256);
    qk_kernel<<<dim3(rows / 16), blk, 0, stream>>>(x, Wt, Wx, bh, qk);
    attn_kernel<<<dim3(rows / 2), blk, 0, stream>>>(x, qk, Wa, ba, out);
}

// Round 4
// 116.247 us; speedup vs baseline: 1.1482x; 1.1482x over previous
//
#include <hip/hip_runtime.h>
#include <hip/hip_bf16.h>

// Problem constants (fixed by setup_inputs)
#define B 4
#define T 1024
#define D 512
#define U 32
#define WIN 64           // attention window (j in [t-32, t+31])
#define EPS 1e-7f

__device__ __forceinline__ float fast_tanh(float z) {
    const float ez = __expf(2.0f * z);
    return 1.0f - 2.0f / (ez + 1.0f);
}

// ---------------------------------------------------------------------------
// Kernel A: qk[row][0:32]  = x[row,:] @ Wt + bh   (q, bias folded)
//           qk[row][32:64] = x[row,:] @ Wx        (k)
// 256 blocks x 512 thr (8 waves). W staged in LDS in two 64 KB K-halves
// (W2[d][0:32]=Wt, [32:64]=Wx). 2 rows/wave (16 rows/block): each
// ds_read_b32 of W feeds 2 FMAs; x read as uniform float4 (L1-hot).
// 8 waves/CU (2/SIMD) vs round-3's 4 — latency hidden by TLP + unroll.
// ---------------------------------------------------------------------------
__global__ __launch_bounds__(512) void qk_kernel(
    const float* __restrict__ x, const float* __restrict__ Wt,
    const float* __restrict__ Wx, const float* __restrict__ bh,
    float* __restrict__ qk)
{
    __shared__ float W2[256][64];        // 64 KB

    const int tid  = threadIdx.x;
    const int lane = tid & 63;
    const int wv   = tid >> 6;           // 0..7
    const int r0   = blockIdx.x * 16 + wv * 2;

    const float bias = (lane < U) ? bh[lane] : 0.0f;
    float acc0 = bias, acc1 = bias;

    for (int h = 0; h < 2; ++h) {
        // ---- stage K-half of Wt|Wx into LDS ----
        const float4* Wt4 = (const float4*)(Wt + (size_t)h * 256 * U);
        const float4* Wx4 = (const float4*)(Wx + (size_t)h * 256 * U);
        #pragma unroll
        for (int i = 0; i < 4; ++i) {
            const int j  = i * 512 + tid;     // float4 index, 0..2047
            const int d  = j >> 3;
            const int u0 = (j & 7) << 2;
            *(float4*)&W2[d][u0]      = Wt4[j];
            *(float4*)&W2[d][32 + u0] = Wx4[j];
        }
        __syncthreads();

        const float* xr0 = x + (size_t)r0 * D + h * 256;
        const float* xr1 = xr0 + D;

        #pragma unroll 8
        for (int d4 = 0; d4 < 64; ++d4) {
            const float4 xa = ((const float4*)xr0)[d4];
            const float4 xb = ((const float4*)xr1)[d4];
            const float w0 = W2[d4 * 4 + 0][lane];
            const float w1 = W2[d4 * 4 + 1][lane];
            const float w2 = W2[d4 * 4 + 2][lane];
            const float w3 = W2[d4 * 4 + 3][lane];
            acc0 = fmaf(xa.x, w0, acc0); acc1 = fmaf(xb.x, w0, acc1);
            acc0 = fmaf(xa.y, w1, acc0); acc1 = fmaf(xb.y, w1, acc1);
            acc0 = fmaf(xa.z, w2, acc0); acc1 = fmaf(xb.z, w2, acc1);
            acc0 = fmaf(xa.w, w3, acc0); acc1 = fmaf(xb.w, w3, acc1);
        }
        __syncthreads();   // before next half overwrites W2
    }

    qk[(size_t)(r0 + 0) * WIN + lane] = acc0;
    qk[(size_t)(r0 + 1) * WIN + lane] = acc1;
}

// ---------------------------------------------------------------------------
// Kernel B: 1024 blocks x 4 waves. Block covers 2 t-pairs; wave = (pair, dh).
// XCD-chunked swizzle: logical block l = (h%8)*128 + h/8 -> each XCD owns a
// contiguous ~512-t range; its x slice (~1.2 MB) stays L2-resident.
// Phase 1: wave dh computes scores for t = ta+dh (its own window, lane = j),
//          writes a[] to LDS. Phase 2 (after barrier): each wave accumulates
//          BOTH t's outputs over its d-half across the 65-row union window —
//          one x load feeds 2 output rows (halves x traffic).
// ---------------------------------------------------------------------------
__global__ __launch_bounds__(256) void attn_kernel(
    const float* __restrict__ x, const float* __restrict__ qk,
    const float* __restrict__ Wa, const float* __restrict__ ba,
    float* __restrict__ out)
{
    __shared__ float A[2][2][64];        // [pairInBlock][t-of-pair][j]

    const int tid  = threadIdx.x;
    const int lane = tid & 63;
    const int wv   = tid >> 6;                       // 0..3
    const int l    = ((blockIdx.x & 7) << 7) + (blockIdx.x >> 3);  // XCD chunk
    const int ps   = wv >> 1;                        // pair slot in block
    const int dh   = wv & 1;                         // d-half
    const int p    = l * 2 + ps;                     // global pair, 0..2047
    const int gta  = p * 2;                          // 0..4094 (even)
    const int b    = gta >> 10;
    const int ta   = gta & (T - 1);                  // even, tb = ta+1 <= 1023
    const int ts   = ta + dh;                        // the t this wave scores

    // ---- Phase 1: scores for ts (lane = window index j) ----
    const float* qrow = qk + (size_t)(b * T + ts) * WIN;
    const int jj = ts - 32 + lane;
    float e = 0.0f;
    if (jj >= 0 && jj < T) {
        const float* krow = qk + (size_t)(b * T + jj) * WIN + U;
        float acc = ba[0];
        #pragma unroll
        for (int i = 0; i < 8; ++i) {
            const float4 kv = ((const float4*)krow)[i];
            const float4 qv = ((const float4*)qrow)[i];
            acc = fmaf(Wa[i * 4 + 0], fast_tanh(qv.x + kv.x), acc);
            acc = fmaf(Wa[i * 4 + 1], fast_tanh(qv.y + kv.y), acc);
            acc = fmaf(Wa[i * 4 + 2], fast_tanh(qv.z + kv.z), acc);
            acc = fmaf(Wa[i * 4 + 3], fast_tanh(qv.w + kv.w), acc);
        }
        e = __expf(acc);
    }
    float s = e;
    #pragma unroll
    for (int off = 32; off > 0; off >>= 1)
        s += __shfl_xor(s, off);
    A[ps][dh][lane] = e / (s + EPS);
    __syncthreads();

    // ---- Phase 2: union window rows ta-32 .. ta+32 (65 rows) ----
    float4 va = make_float4(0.f, 0.f, 0.f, 0.f);
    float4 vb = make_float4(0.f, 0.f, 0.f, 0.f);
    const float* xh = x + (size_t)b * T * D + dh * (D / 2);

    #pragma unroll 4
    for (int m = 0; m <= 64; ++m) {
        const int row = ta - 32 + m;
        if (row < 0 || row >= T) continue;           // OOB rows have weight 0
        const float wa = (m < 64) ? A[ps][0][m] : 0.0f;
        const float wb = (m > 0)  ? A[ps][1][m - 1] : 0.0f;
        const float4 xv = ((const float4*)(xh + (size_t)row * D))[lane];
        va.x = fmaf(wa, xv.x, va.x); vb.x = fmaf(wb, xv.x, vb.x);
        va.y = fmaf(wa, xv.y, va.y); vb.y = fmaf(wb, xv.y, vb.y);
        va.z = fmaf(wa, xv.z, va.z); vb.z = fmaf(wb, xv.z, vb.z);
        va.w = fmaf(wa, xv.w, va.w); vb.w = fmaf(wb, xv.w, vb.w);
    }

    ((float4*)(out + (size_t)(b * T + ta)     * D + dh * (D / 2)))[lane] = va;
    ((float4*)(out + (size_t)(b * T + ta + 1) * D + dh * (D / 2)))[lane] = vb;
}

extern "C" void kernel_launch(void* const* d_in, const int* in_sizes, int n_in,
                              void* d_out, int out_size, void* d_ws, size_t ws_size,
                              hipStream_t stream)
{
    const float* x  = (const float*)d_in[0];
    const float* Wt = (const float*)d_in[1];
    const float* Wx = (const float*)d_in[2];
    const float* bh = (const float*)d_in[3];
    const float* Wa = (const float*)d_in[4];
    const float* ba = (const float*)d_in[5];
    float* out = (float*)d_out;
    float* qk  = (float*)d_ws;   // B*T*64 floats = 1 MB

    qk_kernel<<<dim3(256), dim3(512), 0, stream>>>(x, Wt, Wx, bh, qk);
    attn_kernel<<<dim3(1024), dim3(256), 0, stream>>>(x, qk, Wa, ba, out);
}

// Round 6
// 108.875 us; speedup vs baseline: 1.2260x; 1.0677x over previous
//
#include <hip/hip_runtime.h>
#include <hip/hip_bf16.h>

// Problem constants (fixed by setup_inputs)
#define B 4
#define T 1024
#define D 512
#define U 32
#define WIN 64           // attention window (j in [t-32, t+31])
#define EPS 1e-7f

__device__ __forceinline__ float fast_tanh(float z) {
    const float ez = __expf(2.0f * z);
    return 1.0f - 2.0f / (ez + 1.0f);
}

__device__ __forceinline__ float bcast_lane(float v, int l) {
    return __int_as_float(__builtin_amdgcn_readlane(__float_as_int(v), l));
}

// ---------------------------------------------------------------------------
// Kernel A (v5): qk[row][0:32] = x[row,:]@Wt + bh ; qk[row][32:64] = x@Wx.
// 256 blocks x 512 thr (8 waves, 2 waves/SIMD), 2 rows/wave, 16 rows/block.
// FULL W (128 KB) staged in LDS once (one barrier). Each lane holds its
// 8-element x slice in registers (x[row][lane*8+r]); K-loop broadcasts x[d]
// via compile-time readlane (VALU only). Inner body per d: 1 conflict-free
// ds_read_b32 + 2 readlane + 2 FMA — no per-iteration global loads, no
// vmcnt stalls. Model: ~5 us.
// ---------------------------------------------------------------------------
__global__ __launch_bounds__(512) void qk_kernel(
    const float* __restrict__ x, const float* __restrict__ Wt,
    const float* __restrict__ Wx, const float* __restrict__ bh,
    float* __restrict__ qk)
{
    __shared__ float W2[D][64];          // 128 KB: [d][0:32]=Wt, [32:64]=Wx

    const int tid  = threadIdx.x;
    const int lane = tid & 63;
    const int wv   = tid >> 6;           // 0..7
    const int r0   = blockIdx.x * 16 + wv * 2;

    // ---- stage all of Wt|Wx into LDS (4096 float4 each, 8 per thread) ----
    {
        const float4* Wt4 = (const float4*)Wt;
        const float4* Wx4 = (const float4*)Wx;
        #pragma unroll
        for (int i = 0; i < 8; ++i) {
            const int j  = i * 512 + tid;     // float4 index 0..4095
            const int d  = j >> 3;
            const int u0 = (j & 7) << 2;
            *(float4*)&W2[d][u0]      = Wt4[j];
            *(float4*)&W2[d][32 + u0] = Wx4[j];
        }
    }

    // ---- x slices into registers: xa[r] = x[r0][lane*8+r], xb = row r0+1 --
    const float4* xr0 = (const float4*)(x + (size_t)(r0 + 0) * D);
    const float4* xr1 = (const float4*)(x + (size_t)(r0 + 1) * D);
    const float4 A0 = xr0[lane * 2], A1 = xr0[lane * 2 + 1];
    const float4 B0 = xr1[lane * 2], B1 = xr1[lane * 2 + 1];
    const float xa[8] = {A0.x, A0.y, A0.z, A0.w, A1.x, A1.y, A1.z, A1.w};
    const float xb[8] = {B0.x, B0.y, B0.z, B0.w, B1.x, B1.y, B1.z, B1.w};

    __syncthreads();

    const float bias = (lane < U) ? bh[lane] : 0.0f;
    float acc0 = bias, acc1 = bias;

    #pragma unroll
    for (int l = 0; l < 64; ++l) {
        #pragma unroll
        for (int r = 0; r < 8; ++r) {
            const float w  = W2[l * 8 + r][lane];
            const float s0 = bcast_lane(xa[r], l);
            const float s1 = bcast_lane(xb[r], l);
            acc0 = fmaf(s0, w, acc0);
            acc1 = fmaf(s1, w, acc1);
        }
    }

    qk[(size_t)(r0 + 0) * WIN + lane] = acc0;
    qk[(size_t)(r0 + 1) * WIN + lane] = acc1;
}

// ---------------------------------------------------------------------------
// Kernel B: UNCHANGED from round 4 (A/B isolation: Δdur == Δqk).
// ---------------------------------------------------------------------------
__global__ __launch_bounds__(256) void attn_kernel(
    const float* __restrict__ x, const float* __restrict__ qk,
    const float* __restrict__ Wa, const float* __restrict__ ba,
    float* __restrict__ out)
{
    __shared__ float A[2][2][64];        // [pairInBlock][t-of-pair][j]

    const int tid  = threadIdx.x;
    const int lane = tid & 63;
    const int wv   = tid >> 6;                       // 0..3
    const int l    = ((blockIdx.x & 7) << 7) + (blockIdx.x >> 3);  // XCD chunk
    const int ps   = wv >> 1;                        // pair slot in block
    const int dh   = wv & 1;                         // d-half
    const int p    = l * 2 + ps;                     // global pair, 0..2047
    const int gta  = p * 2;                          // 0..4094 (even)
    const int b    = gta >> 10;
    const int ta   = gta & (T - 1);                  // even, tb = ta+1 <= 1023
    const int ts   = ta + dh;                        // the t this wave scores

    // ---- Phase 1: scores for ts (lane = window index j) ----
    const float* qrow = qk + (size_t)(b * T + ts) * WIN;
    const int jj = ts - 32 + lane;
    float e = 0.0f;
    if (jj >= 0 && jj < T) {
        const float* krow = qk + (size_t)(b * T + jj) * WIN + U;
        float acc = ba[0];
        #pragma unroll
        for (int i = 0; i < 8; ++i) {
            const float4 kv = ((const float4*)krow)[i];
            const float4 qv = ((const float4*)qrow)[i];
            acc = fmaf(Wa[i * 4 + 0], fast_tanh(qv.x + kv.x), acc);
            acc = fmaf(Wa[i * 4 + 1], fast_tanh(qv.y + kv.y), acc);
            acc = fmaf(Wa[i * 4 + 2], fast_tanh(qv.z + kv.z), acc);
            acc = fmaf(Wa[i * 4 + 3], fast_tanh(qv.w + kv.w), acc);
        }
        e = __expf(acc);
    }
    float s = e;
    #pragma unroll
    for (int off = 32; off > 0; off >>= 1)
        s += __shfl_xor(s, off);
    A[ps][dh][lane] = e / (s + EPS);
    __syncthreads();

    // ---- Phase 2: union window rows ta-32 .. ta+32 (65 rows) ----
    float4 va = make_float4(0.f, 0.f, 0.f, 0.f);
    float4 vb = make_float4(0.f, 0.f, 0.f, 0.f);
    const float* xh = x + (size_t)b * T * D + dh * (D / 2);

    #pragma unroll 4
    for (int m = 0; m <= 64; ++m) {
        const int row = ta - 32 + m;
        if (row < 0 || row >= T) continue;           // OOB rows have weight 0
        const float wa = (m < 64) ? A[ps][0][m] : 0.0f;
        const float wb = (m > 0)  ? A[ps][1][m - 1] : 0.0f;
        const float4 xv = ((const float4*)(xh + (size_t)row * D))[lane];
        va.x = fmaf(wa, xv.x, va.x); vb.x = fmaf(wb, xv.x, vb.x);
        va.y = fmaf(wa, xv.y, va.y); vb.y = fmaf(wb, xv.y, vb.y);
        va.z = fmaf(wa, xv.z, va.z); vb.z = fmaf(wb, xv.z, vb.z);
        va.w = fmaf(wa, xv.w, va.w); vb.w = fmaf(wb, xv.w, vb.w);
    }

    ((float4*)(out + (size_t)(b * T + ta)     * D + dh * (D / 2)))[lane] = va;
    ((float4*)(out + (size_t)(b * T + ta + 1) * D + dh * (D / 2)))[lane] = vb;
}

extern "C" void kernel_launch(void* const* d_in, const int* in_sizes, int n_in,
                              void* d_out, int out_size, void* d_ws, size_t ws_size,
                              hipStream_t stream)
{
    const float* x  = (const float*)d_in[0];
    const float* Wt = (const float*)d_in[1];
    const float* Wx = (const float*)d_in[2];
    const float* bh = (const float*)d_in[3];
    const float* Wa = (const float*)d_in[4];
    const float* ba = (const float*)d_in[5];
    float* out = (float*)d_out;
    float* qk  = (float*)d_ws;   // B*T*64 floats = 1 MB

    qk_kernel<<<dim3(256), dim3(512), 0, stream>>>(x, Wt, Wx, bh, qk);
    attn_kernel<<<dim3(1024), dim3(256), 0, stream>>>(x, qk, Wa, ba, out);
}

// Round 7
// 96.524 us; speedup vs baseline: 1.3828x; 1.1280x over previous
//
#include <hip/hip_runtime.h>
#include <hip/hip_bf16.h>

// Problem constants (fixed by setup_inputs)
#define B 4
#define T 1024
#define D 512
#define U 32
#define WIN 64           // attention window (j in [t-32, t+31])
#define EPS 1e-7f

__device__ __forceinline__ float fast_tanh(float z) {
    const float ez = __expf(2.0f * z);
    return 1.0f - 2.0f / (ez + 1.0f);
}

__device__ __forceinline__ float bcast_lane(float v, int l) {
    return __int_as_float(__builtin_amdgcn_readlane(__float_as_int(v), l));
}

// ---------------------------------------------------------------------------
// Kernel A (v5, UNCHANGED from round 6 — control for A/B isolation).
// ---------------------------------------------------------------------------
__global__ __launch_bounds__(512) void qk_kernel(
    const float* __restrict__ x, const float* __restrict__ Wt,
    const float* __restrict__ Wx, const float* __restrict__ bh,
    float* __restrict__ qk)
{
    __shared__ float W2[D][64];          // 128 KB: [d][0:32]=Wt, [32:64]=Wx

    const int tid  = threadIdx.x;
    const int lane = tid & 63;
    const int wv   = tid >> 6;           // 0..7
    const int r0   = blockIdx.x * 16 + wv * 2;

    {
        const float4* Wt4 = (const float4*)Wt;
        const float4* Wx4 = (const float4*)Wx;
        #pragma unroll
        for (int i = 0; i < 8; ++i) {
            const int j  = i * 512 + tid;     // float4 index 0..4095
            const int d  = j >> 3;
            const int u0 = (j & 7) << 2;
            *(float4*)&W2[d][u0]      = Wt4[j];
            *(float4*)&W2[d][32 + u0] = Wx4[j];
        }
    }

    const float4* xr0 = (const float4*)(x + (size_t)(r0 + 0) * D);
    const float4* xr1 = (const float4*)(x + (size_t)(r0 + 1) * D);
    const float4 A0 = xr0[lane * 2], A1 = xr0[lane * 2 + 1];
    const float4 B0 = xr1[lane * 2], B1 = xr1[lane * 2 + 1];
    const float xa[8] = {A0.x, A0.y, A0.z, A0.w, A1.x, A1.y, A1.z, A1.w};
    const float xb[8] = {B0.x, B0.y, B0.z, B0.w, B1.x, B1.y, B1.z, B1.w};

    __syncthreads();

    const float bias = (lane < U) ? bh[lane] : 0.0f;
    float acc0 = bias, acc1 = bias;

    #pragma unroll
    for (int l = 0; l < 64; ++l) {
        #pragma unroll
        for (int r = 0; r < 8; ++r) {
            const float w  = W2[l * 8 + r][lane];
            const float s0 = bcast_lane(xa[r], l);
            const float s1 = bcast_lane(xb[r], l);
            acc0 = fmaf(s0, w, acc0);
            acc1 = fmaf(s1, w, acc1);
        }
    }

    qk[(size_t)(r0 + 0) * WIN + lane] = acc0;
    qk[(size_t)(r0 + 1) * WIN + lane] = acc1;
}

// ---------------------------------------------------------------------------
// Kernel B v2: phase 2 made BRANCH-FREE. OOB window rows have weight exactly
// 0 (phase 1 sets e=0), so the row index is CLAMPED to [0,T-1] instead of
// guarded — every load is unconditional, the full 65-iter loop unrolls, and
// the compiler can batch loads (many in flight) instead of the previous
// load->wait->fma serial chain (guarded loads can't be hoisted: might fault).
// A-weights pulled from LDS into registers once, broadcast via readlane.
// ---------------------------------------------------------------------------
__global__ __launch_bounds__(256) void attn_kernel(
    const float* __restrict__ x, const float* __restrict__ qk,
    const float* __restrict__ Wa, const float* __restrict__ ba,
    float* __restrict__ out)
{
    __shared__ float A[2][2][64];        // [pairInBlock][t-of-pair][j]

    const int tid  = threadIdx.x;
    const int lane = tid & 63;
    const int wv   = tid >> 6;                       // 0..3
    const int l    = ((blockIdx.x & 7) << 7) + (blockIdx.x >> 3);  // XCD chunk
    const int ps   = wv >> 1;                        // pair slot in block
    const int dh   = wv & 1;                         // d-half
    const int p    = l * 2 + ps;                     // global pair, 0..2047
    const int gta  = p * 2;                          // 0..4094 (even)
    const int b    = gta >> 10;
    const int ta   = gta & (T - 1);                  // even, tb = ta+1 <= 1023
    const int ts   = ta + dh;                        // the t this wave scores

    // ---- Phase 1: scores for ts (lane = window index j) ----
    const float* qrow = qk + (size_t)(b * T + ts) * WIN;
    const int jj = ts - 32 + lane;
    float e = 0.0f;
    if (jj >= 0 && jj < T) {
        const float* krow = qk + (size_t)(b * T + jj) * WIN + U;
        float acc = ba[0];
        #pragma unroll
        for (int i = 0; i < 8; ++i) {
            const float4 kv = ((const float4*)krow)[i];
            const float4 qv = ((const float4*)qrow)[i];
            acc = fmaf(Wa[i * 4 + 0], fast_tanh(qv.x + kv.x), acc);
            acc = fmaf(Wa[i * 4 + 1], fast_tanh(qv.y + kv.y), acc);
            acc = fmaf(Wa[i * 4 + 2], fast_tanh(qv.z + kv.z), acc);
            acc = fmaf(Wa[i * 4 + 3], fast_tanh(qv.w + kv.w), acc);
        }
        e = __expf(acc);
    }
    float s = e;
    #pragma unroll
    for (int off = 32; off > 0; off >>= 1)
        s += __shfl_xor(s, off);
    A[ps][dh][lane] = e / (s + EPS);
    __syncthreads();

    // Weight vectors into registers (2 LDS reads total; broadcast by readlane)
    const float waL = A[ps][0][lane];   // weights for t = ta,   j = lane
    const float wbL = A[ps][1][lane];   // weights for t = ta+1, j = lane

    // ---- Phase 2: union window rows ta-32 .. ta+32 (65 rows), branch-free --
    float4 va = make_float4(0.f, 0.f, 0.f, 0.f);
    float4 vb = make_float4(0.f, 0.f, 0.f, 0.f);
    const float* xh = x + (size_t)b * T * D + dh * (D / 2);

    #pragma unroll
    for (int m = 0; m <= 64; ++m) {
        int row = ta - 32 + m;
        row = (row < 0) ? 0 : row;
        row = (row > T - 1) ? (T - 1) : row;         // clamped: load always safe
        const float wa = (m < 64) ? bcast_lane(waL, m) : 0.0f;
        const float wb = (m > 0)  ? bcast_lane(wbL, m - 1) : 0.0f;
        const float4 xv = ((const float4*)(xh + (size_t)row * D))[lane];
        va.x = fmaf(wa, xv.x, va.x); vb.x = fmaf(wb, xv.x, vb.x);
        va.y = fmaf(wa, xv.y, va.y); vb.y = fmaf(wb, xv.y, vb.y);
        va.z = fmaf(wa, xv.z, va.z); vb.z = fmaf(wb, xv.z, vb.z);
        va.w = fmaf(wa, xv.w, va.w); vb.w = fmaf(wb, xv.w, vb.w);
    }

    ((float4*)(out + (size_t)(b * T + ta)     * D + dh * (D / 2)))[lane] = va;
    ((float4*)(out + (size_t)(b * T + ta + 1) * D + dh * (D / 2)))[lane] = vb;
}

extern "C" void kernel_launch(void* const* d_in, const int* in_sizes, int n_in,
                              void* d_out, int out_size, void* d_ws, size_t ws_size,
                              hipStream_t stream)
{
    const float* x  = (const float*)d_in[0];
    const float* Wt = (const float*)d_in[1];
    const float* Wx = (const float*)d_in[2];
    const float* bh = (const float*)d_in[3];
    const float* Wa = (const float*)d_in[4];
    const float* ba = (const float*)d_in[5];
    float* out = (float*)d_out;
    float* qk  = (float*)d_ws;   // B*T*64 floats = 1 MB

    qk_kernel<<<dim3(256), dim3(512), 0, stream>>>(x, Wt, Wx, bh, qk);
    attn_kernel<<<dim3(1024), dim3(256), 0, stream>>>(x, qk, Wa, ba, out);
}